// Round 3
// baseline (224.211 us; speedup 1.0000x reference)
//
#include <hip/hip_runtime.h>

#define H      128
#define OBSROW 141
#define GPB    16     // graphs per block (MFMA M dimension)
#define NT     512    // 8 waves; each wave owns 16 output channels (one 16x16 o-subtile)

typedef __bf16 bf16x8 __attribute__((ext_vector_type(8)));
typedef float  f32x4  __attribute__((ext_vector_type(4)));

__device__ __forceinline__ float eluf(float v) {
    return v > 0.0f ? v : (__expf(v) - 1.0f);
}
__device__ __forceinline__ f32x4 mf(bf16x8 a, bf16x8 b, f32x4 c) {
    return __builtin_amdgcn_mfma_f32_16x16x32_bf16(a, b, c, 0, 0, 0);
}
// elu 4 floats -> 4 bf16, one aligned b64 store
__device__ __forceinline__ void store_pk4(unsigned short* dst, f32x4 a) {
    union { unsigned short u[4]; unsigned long long v; } pk;
    #pragma unroll
    for (int r = 0; r < 4; r++) {
        __bf16 b = (__bf16)eluf(a[r]);
        pk.u[r] = *(unsigned short*)&b;
    }
    *(unsigned long long*)dst = pk.v;
}

// ws (bf16 elems): [0)Wrel 3*16384 | [49152)Wroot 3*16384 | [98304)We_b pad[128][64] | [106496)We_j pad[128][32]
#define WS_ROOT 49152
#define WS_EB   98304
#define WS_EJ   106496
#define WS_TOT  110592

__global__ void convert_weights(const float* __restrict__ Wr, const float* __restrict__ Wo,
                                const float* __restrict__ Web, const float* __restrict__ Wej,
                                __bf16* __restrict__ ws) {
    const int i = blockIdx.x * 256 + threadIdx.x;
    if (i < WS_ROOT) {
        ws[i] = (__bf16)Wr[i];
    } else if (i < WS_EB) {
        ws[i] = (__bf16)Wo[i - WS_ROOT];
    } else if (i < WS_EJ) {
        const int j = i - WS_EB, o = j >> 6, f = j & 63;
        ws[i] = (__bf16)(f < 33 ? Web[o*33 + f] : 0.0f);
    } else if (i < WS_TOT) {
        const int j = i - WS_EJ, o = j >> 5, f = j & 31;
        ws[i] = (__bf16)(f < 9 ? Wej[o*9 + f] : 0.0f);
    }
}

// X layout: [node 13][hc 16][graph 16][hi 8] bf16; k (= channel) = hc*8+hi
// Gathered features are OVERLAID into the top of Xs (bytes [38912,53248) = ushort
// index 19456..26624, i.e. the node 9..12 region). Nodes 9..12 encoder outputs are
// therefore computed into registers and stored only after a barrier.
#define G0U 19456   // gathered-feature base (ushort index): joints jj at G0U+jj*512, base at G0U+6144

__launch_bounds__(NT, 6)   // 6 waves/EU -> ~85-reg cap; 3 blocks/CU (LDS 53248*3 = 159744)
__global__ void gnn_fused(const float* __restrict__ obs,
                          const float* __restrict__ be_b, const float* __restrict__ be_j,
                          const float* __restrict__ b_rel,
                          const float* __restrict__ W_dec, const float* __restrict__ b_dec,
                          const __bf16* __restrict__ wsb,
                          float* __restrict__ out, int B)
{
    __shared__ __align__(16) unsigned short Xs[13*2048];   // 53248 B total (single allocation)

    const int tid  = threadIdx.x;
    const int wave = tid >> 6;     // 0..7 -> channels [wave*16, wave*16+16)
    const int lane = tid & 63;
    const int q    = lane >> 4;    // k-quarter (inputs) / channel-quad (output)
    const int c    = lane & 15;    // graph (B-side) == weight output-row offset (A-side)
    const int g0   = blockIdx.x * GPB;

    static constexpr int ODEG[13]    = {4,2,2,1,2,2,1,2,2,1,2,2,1};
    static constexpr int ODST[13][4] = {
        {1,4,7,10},{0,2,0,0},{1,3,0,0},{2,0,0,0},{0,5,0,0},{4,6,0,0},{5,0,0,0},
        {0,8,0,0},{7,9,0,0},{8,0,0,0},{0,11,0,0},{10,12,0,0},{11,0,0,0}};

    // swapped-operand output: lane (q,c) holds graph c, channels o = wave*16 + q*4 + r
    const int hcd  = wave*2 + (q>>1);          // destination hc
    const int wofs = c*8 + (q&1)*4;            // graph*8 + hi base (ushort units)

    // ---------------- stage 0: coalesced obs copy global -> LDS raw (bytes [0,9024)) ----
    {
        float* raw = (float*)Xs;
        for (int i = tid; i < GPB*OBSROW; i += NT) {
            const int g = i / OBSROW;
            raw[i] = ((g0 + g) < B) ? obs[(g0+g)*OBSROW + (i - g*OBSROW)] : 0.0f;
        }
    }
    __syncthreads();

    // ---------------- stage 1: gather + cvt raw -> gathered (top of Xs) ----------------
    {
        const float* raw = (const float*)Xs;
        // joints at G0U + jj*512 + fc*128 + g*8 + hi
        for (int s = tid; s < 6144; s += NT) {
            const int jj = s >> 9, rem = s & 511;
            const int fc = rem >> 7, g = (rem >> 3) & 15, hi = rem & 7;
            const int f = fc*8 + hi;
            float v = 0.0f;
            if (f < 9)
                v = raw[g*OBSROW + (f/3)*47 + 9 + (f%3)*12 + jj];
            *(__bf16*)&Xs[G0U + s] = (__bf16)v;
        }
        // base at G0U + 6144 + fc*128 + g*8 + hi (K padded to 64)
        for (int s = tid; s < 1024; s += NT) {
            const int fc = s >> 7, rem = s & 127, g = rem >> 3, hi = rem & 7;
            const int f = fc*8 + hi;
            float v = 0.0f;
            if (f < 33) {
                const int tt = f / 11, i2 = f % 11;
                v = raw[g*OBSROW + tt*47 + (i2 < 9 ? i2 : 36 + i2)];
            }
            *(__bf16*)&Xs[G0U + 6144 + s] = (__bf16)v;
        }
    }
    __syncthreads();

    // ---------------- encoders (A = weights, B = features) ----------------
    // Nodes 0..8 outputs (bytes [0,36864)) don't overlap gathered ([38912,53248)) -> direct.
    // Nodes 9..12 outputs overlap gathered -> accumulate in regs, store after barrier.
    {
        const int orow = wave*16 + c;
        // node 0 (base), K=64 padded -> 2 MFMAs, direct store
        {
            const bf16x8 u0 = *(const bf16x8*)(wsb + WS_EB + orow*64 + q*8);
            const bf16x8 u1 = *(const bf16x8*)(wsb + WS_EB + orow*64 + 32 + q*8);
            const bf16x8 a0 = *(const bf16x8*)&Xs[G0U + 6144 + q*128 + c*8];
            const bf16x8 a1 = *(const bf16x8*)&Xs[G0U + 6144 + 512 + q*128 + c*8];
            const float4 b4 = *(const float4*)&be_b[wave*16 + q*4];
            f32x4 acc = {b4.x, b4.y, b4.z, b4.w};
            acc = mf(u0, a0, acc);
            acc = mf(u1, a1, acc);
            store_pk4(&Xs[hcd*128 + wofs], acc);
        }
        // joints, K=32 -> 1 MFMA each
        const bf16x8 uj = *(const bf16x8*)(wsb + WS_EJ + orow*32 + q*8);
        const float4 b4 = *(const float4*)&be_j[wave*16 + q*4];
        const f32x4 bias = {b4.x, b4.y, b4.z, b4.w};
        // jj = 0..7 -> nodes 1..8: direct
        #pragma unroll
        for (int jj = 0; jj < 8; jj++) {
            const bf16x8 a = *(const bf16x8*)&Xs[G0U + jj*512 + q*128 + c*8];
            f32x4 acc = bias;
            acc = mf(uj, a, acc);
            store_pk4(&Xs[(1+jj)*2048 + hcd*128 + wofs], acc);
        }
        // jj = 8..11 -> nodes 9..12: deferred
        f32x4 dacc[4];
        #pragma unroll
        for (int t = 0; t < 4; t++) {
            const bf16x8 a = *(const bf16x8*)&Xs[G0U + (8+t)*512 + q*128 + c*8];
            dacc[t] = bias;
            dacc[t] = mf(uj, a, dacc[t]);
        }
        __syncthreads();   // all gathered-feature reads complete
        #pragma unroll
        for (int t = 0; t < 4; t++)
            store_pk4(&Xs[(9+t)*2048 + hcd*128 + wofs], dacc[t]);
    }
    __syncthreads();

    // ---------------- 3 GraphConv layers ----------------
    // B-frag (X) for (n,ks): Xs + n*2048 + ks*512 + q*128 + c*8 (wave-contiguous 1KB)
    // A-frag (W) for ks:     w + (wave*16+c)*128 + ks*32 + q*8
    const unsigned short* xr = Xs + q*128 + c*8;
    #pragma unroll 1
    for (int l = 0; l < 3; l++) {
        const __bf16* wr = wsb + l*16384 + (wave*16 + c)*128 + q*8;
        const __bf16* wo = wsb + WS_ROOT + l*16384 + (wave*16 + c)*128 + q*8;
        const float4 b4 = *(const float4*)&b_rel[l*H + wave*16 + q*4];
        const f32x4 bias = {b4.x, b4.y, b4.z, b4.w};

        f32x4 acc[13];
        #pragma unroll
        for (int n = 0; n < 13; n++) acc[n] = bias;

        #pragma unroll 1
        for (int h = 0; h < 2; h++) {
            const bf16x8 br0 = *(const bf16x8*)(wr + h*64);
            const bf16x8 br1 = *(const bf16x8*)(wr + h*64 + 32);
            const bf16x8 bo0 = *(const bf16x8*)(wo + h*64);
            const bf16x8 bo1 = *(const bf16x8*)(wo + h*64 + 32);
            const unsigned short* xh = xr + h*1024;
            #pragma unroll
            for (int n = 0; n < 13; n++) {
                const bf16x8 xa0 = *(const bf16x8*)(xh + n*2048);
                const bf16x8 xa1 = *(const bf16x8*)(xh + n*2048 + 512);
                // root contribution straight into acc[n]
                acc[n] = mf(bo0, xa0, acc[n]);
                acc[n] = mf(bo1, xa1, acc[n]);
                // rel contribution into transient y, scatter to out-neighbors
                f32x4 y = {0.f,0.f,0.f,0.f};
                y = mf(br0, xa0, y);
                y = mf(br1, xa1, y);
                #pragma unroll
                for (int e = 0; e < 4; e++)
                    if (e < ODEG[n]) acc[ODST[n][e]] += y;
            }
        }
        __syncthreads();   // all X reads done
        // epilogue: elu + pack -> one conflict-free b64 store per node
        #pragma unroll
        for (int n = 0; n < 13; n++)
            store_pk4(&Xs[n*2048 + hcd*128 + wofs], acc[n]);
        __syncthreads();   // new X visible
    }

    // ---------------- decoder: out[g][j] = x[j+1]·W_dec + b_dec ----------------
    {
        const unsigned short* xdec = Xs + q*512 + c*8;
        float wd[32];
        #pragma unroll
        for (int i4 = 0; i4 < 8; i4++) {
            const float4 wv = *(const float4*)&W_dec[q*32 + i4*4];
            wd[i4*4+0] = wv.x; wd[i4*4+1] = wv.y; wd[i4*4+2] = wv.z; wd[i4*4+3] = wv.w;
        }
        const float bd = b_dec[0];
        for (int j = wave; j < 12; j += 8) {    // waves 0..3 do two joints, 4..7 one
            float s = 0.0f;
            #pragma unroll
            for (int hq = 0; hq < 4; hq++) {    // lane covers h = q*32 + hq*8 + hi
                const bf16x8 xv = *(const bf16x8*)(xdec + (j+1)*2048 + hq*128);
                #pragma unroll
                for (int hi2 = 0; hi2 < 8; hi2++)
                    s += (float)xv[hi2] * wd[hq*8 + hi2];
            }
            s += __shfl_xor(s, 16);
            s += __shfl_xor(s, 32);
            if (q == 0 && (g0 + c) < B)
                out[(g0 + c)*12 + j] = s + bd;
        }
    }
}

extern "C" void kernel_launch(void* const* d_in, const int* in_sizes, int n_in,
                              void* d_out, int out_size, void* d_ws, size_t ws_size,
                              hipStream_t stream) {
    const float* obs   = (const float*)d_in[0];
    const float* We_b  = (const float*)d_in[1];
    const float* be_b  = (const float*)d_in[2];
    const float* We_j  = (const float*)d_in[3];
    const float* be_j  = (const float*)d_in[4];
    const float* W_rel = (const float*)d_in[5];
    const float* W_root= (const float*)d_in[6];
    const float* b_rel = (const float*)d_in[7];
    const float* W_dec = (const float*)d_in[8];
    const float* b_dec = (const float*)d_in[9];
    float* out = (float*)d_out;
    __bf16* wsb = (__bf16*)d_ws;

    const int B = in_sizes[0] / OBSROW;
    convert_weights<<<(WS_TOT + 255) / 256, 256, 0, stream>>>(W_rel, W_root, We_b, We_j, wsb);
    const int blocks = (B + GPB - 1) / GPB;
    gnn_fused<<<blocks, NT, 0, stream>>>(obs, be_b, be_j, b_rel, W_dec, b_dec,
                                         wsb, out, B);
}

// Round 4
// 216.956 us; speedup vs baseline: 1.0334x; 1.0334x over previous
//
#include <hip/hip_runtime.h>

#define H      128
#define OBSROW 141
#define GPB    16     // graphs per block (MFMA M dimension)
#define NT     256    // 4 waves; each wave owns 32 output channels (2 x 16-subtiles)

typedef __bf16 bf16x8 __attribute__((ext_vector_type(8)));
typedef float  f32x4  __attribute__((ext_vector_type(4)));

__device__ __forceinline__ float eluf(float v) {
    return v > 0.0f ? v : (__expf(v) - 1.0f);
}
__device__ __forceinline__ f32x4 mf(bf16x8 a, bf16x8 b, f32x4 c) {
    return __builtin_amdgcn_mfma_f32_16x16x32_bf16(a, b, c, 0, 0, 0);
}
// elu 4 floats -> 4 bf16, one aligned b64 store
__device__ __forceinline__ void store_pk4(unsigned short* dst, f32x4 a) {
    union { unsigned short u[4]; unsigned long long v; } pk;
    #pragma unroll
    for (int r = 0; r < 4; r++) {
        __bf16 b = (__bf16)eluf(a[r]);
        pk.u[r] = *(unsigned short*)&b;
    }
    *(unsigned long long*)dst = pk.v;
}

// ws (bf16 elems): [0)Wrel 3*16384 | [49152)Wroot 3*16384 | [98304)We_b pad[128][64] | [106496)We_j pad[128][32]
#define WS_ROOT 49152
#define WS_EB   98304
#define WS_EJ   106496
#define WS_TOT  110592

__global__ void convert_weights(const float* __restrict__ Wr, const float* __restrict__ Wo,
                                const float* __restrict__ Web, const float* __restrict__ Wej,
                                __bf16* __restrict__ ws) {
    const int i = blockIdx.x * 256 + threadIdx.x;
    if (i < WS_ROOT) {
        ws[i] = (__bf16)Wr[i];
    } else if (i < WS_EB) {
        ws[i] = (__bf16)Wo[i - WS_ROOT];
    } else if (i < WS_EJ) {
        const int j = i - WS_EB, o = j >> 6, f = j & 63;
        ws[i] = (__bf16)(f < 33 ? Web[o*33 + f] : 0.0f);
    } else if (i < WS_TOT) {
        const int j = i - WS_EJ, o = j >> 5, f = j & 31;
        ws[i] = (__bf16)(f < 9 ? Wej[o*9 + f] : 0.0f);
    }
}

// X layout: [node 13][hc 16][graph 16][hi 8] bf16; k (= channel) = hc*8+hi
// Gathered features OVERLAY the top of Xs: ushort [19456, 26624) = node 9..12 region.
// Encoder outputs for nodes 9..12 are computed into registers, stored after a barrier.
#define G0U 19456   // joints jj at G0U+jj*512, base at G0U+6144

__launch_bounds__(NT, 3)   // 3 waves/EU -> 170-reg cap (natural demand ~104: no spill);
                           // 3 blocks/CU (LDS 53248*3 = 159744 <= 163840)
__global__ void gnn_fused(const float* __restrict__ obs,
                          const float* __restrict__ be_b, const float* __restrict__ be_j,
                          const float* __restrict__ b_rel,
                          const float* __restrict__ W_dec, const float* __restrict__ b_dec,
                          const __bf16* __restrict__ wsb,
                          float* __restrict__ out, int B)
{
    __shared__ __align__(16) unsigned short Xs[13*2048];   // 53248 B total

    const int tid  = threadIdx.x;
    const int wave = tid >> 6;     // 0..3 -> channels [wave*32, wave*32+32)
    const int lane = tid & 63;
    const int q    = lane >> 4;    // k-quarter (inputs) / channel-quad (output)
    const int c    = lane & 15;    // graph (B-side) == weight output-row offset (A-side)
    const int g0   = blockIdx.x * GPB;

    static constexpr int ODEG[13]    = {4,2,2,1,2,2,1,2,2,1,2,2,1};
    static constexpr int ODST[13][4] = {
        {1,4,7,10},{0,2,0,0},{1,3,0,0},{2,0,0,0},{0,5,0,0},{4,6,0,0},{5,0,0,0},
        {0,8,0,0},{7,9,0,0},{8,0,0,0},{0,11,0,0},{10,12,0,0},{11,0,0,0}};

    // swapped-operand output: lane (q,c) holds graph c, channels o = wave*32+s*16+q*4+r
    const int hcs0 = wave*4 + (q>>1);          // hc for s=0 (s adds 2)
    const int wofs = c*8 + (q&1)*4;            // graph*8 + hi base (ushort units)

    // ---------------- stage 0: coalesced obs copy global -> LDS raw (bytes [0,9024)) ----
    {
        float* raw = (float*)Xs;
        for (int i = tid; i < GPB*OBSROW; i += NT) {
            const int g = i / OBSROW;
            raw[i] = ((g0 + g) < B) ? obs[(g0+g)*OBSROW + (i - g*OBSROW)] : 0.0f;
        }
    }
    __syncthreads();

    // ---------------- stage 1: gather + cvt raw -> gathered (top of Xs) ----------------
    {
        const float* raw = (const float*)Xs;
        for (int s = tid; s < 6144; s += NT) {
            const int jj = s >> 9, rem = s & 511;
            const int fc = rem >> 7, g = (rem >> 3) & 15, hi = rem & 7;
            const int f = fc*8 + hi;
            float v = 0.0f;
            if (f < 9)
                v = raw[g*OBSROW + (f/3)*47 + 9 + (f%3)*12 + jj];
            *(__bf16*)&Xs[G0U + s] = (__bf16)v;
        }
        for (int s = tid; s < 1024; s += NT) {
            const int fc = s >> 7, rem = s & 127, g = rem >> 3, hi = rem & 7;
            const int f = fc*8 + hi;
            float v = 0.0f;
            if (f < 33) {
                const int tt = f / 11, i2 = f % 11;
                v = raw[g*OBSROW + tt*47 + (i2 < 9 ? i2 : 36 + i2)];
            }
            *(__bf16*)&Xs[G0U + 6144 + s] = (__bf16)v;
        }
    }
    __syncthreads();

    // ---------------- encoders (A = weights, B = features) ----------------
    // Nodes 0..8 outputs (ushort [0,18432)) don't overlap gathered ([19456,26624)) -> direct.
    // Nodes 9..12 outputs overlap gathered -> accumulate in regs, store after barrier.
    {
        const int orow = wave*32 + c;
        // node 0 (base), K=64 padded
        const bf16x8 a0 = *(const bf16x8*)&Xs[G0U + 6144 + q*128 + c*8];
        const bf16x8 a1 = *(const bf16x8*)&Xs[G0U + 6144 + 512 + q*128 + c*8];
        #pragma unroll
        for (int s = 0; s < 2; s++) {
            const bf16x8 u0 = *(const bf16x8*)(wsb + WS_EB + (orow + s*16)*64 + q*8);
            const bf16x8 u1 = *(const bf16x8*)(wsb + WS_EB + (orow + s*16)*64 + 32 + q*8);
            const float4 b4 = *(const float4*)&be_b[wave*32 + s*16 + q*4];
            f32x4 acc = {b4.x, b4.y, b4.z, b4.w};
            acc = mf(u0, a0, acc);
            acc = mf(u1, a1, acc);
            store_pk4(&Xs[(hcs0 + s*2)*128 + wofs], acc);
        }
        // joints 0..11, K=32; hoist the two weight frags and biases
        bf16x8 uj[2];
        f32x4 bias[2];
        #pragma unroll
        for (int s = 0; s < 2; s++) {
            uj[s] = *(const bf16x8*)(wsb + WS_EJ + (orow + s*16)*32 + q*8);
            const float4 b4 = *(const float4*)&be_j[wave*32 + s*16 + q*4];
            bias[s] = (f32x4){b4.x, b4.y, b4.z, b4.w};
        }
        f32x4 dacc[2][4];   // deferred: nodes 9..12
        #pragma unroll
        for (int jj = 0; jj < 12; jj++) {
            const bf16x8 a = *(const bf16x8*)&Xs[G0U + jj*512 + q*128 + c*8];
            #pragma unroll
            for (int s = 0; s < 2; s++) {
                f32x4 acc = bias[s];
                acc = mf(uj[s], a, acc);
                if (jj < 8)
                    store_pk4(&Xs[(1+jj)*2048 + (hcs0 + s*2)*128 + wofs], acc);
                else
                    dacc[s][jj-8] = acc;
            }
        }
        __syncthreads();   // all gathered-feature reads complete
        #pragma unroll
        for (int t = 0; t < 4; t++) {
            store_pk4(&Xs[(9+t)*2048 +  hcs0     *128 + wofs], dacc[0][t]);
            store_pk4(&Xs[(9+t)*2048 + (hcs0+2)  *128 + wofs], dacc[1][t]);
        }
    }
    __syncthreads();

    // ---------------- 3 GraphConv layers ----------------
    // B-frag (X) for (n,ks): Xs + n*2048 + ks*512 + q*128 + c*8 (wave-contiguous 1KB)
    const unsigned short* xb_base = Xs + q*128 + c*8;
    #pragma unroll 1
    for (int l = 0; l < 3; l++) {
        const __bf16* wr = wsb + l*16384;            // W_rel[l][o][h]
        const __bf16* wo = wsb + WS_ROOT + l*16384;  // W_root[l][o][h]
        bf16x8 Wr[2][4], Wt[2][4];
        #pragma unroll
        for (int s = 0; s < 2; s++) {
            const int row = (wave*32 + s*16 + c)*128 + q*8;
            #pragma unroll
            for (int ks = 0; ks < 4; ks++) {
                Wr[s][ks] = *(const bf16x8*)(wr + row + ks*32);
                Wt[s][ks] = *(const bf16x8*)(wo + row + ks*32);
            }
        }
        f32x4 acc[13][2];
        #pragma unroll
        for (int s = 0; s < 2; s++) {
            const float4 b4 = *(const float4*)&b_rel[l*H + wave*32 + s*16 + q*4];
            const f32x4 bias = {b4.x, b4.y, b4.z, b4.w};
            #pragma unroll
            for (int n = 0; n < 13; n++) acc[n][s] = bias;
        }
        #pragma unroll
        for (int n = 0; n < 13; n++) {
            bf16x8 xb[4];
            #pragma unroll
            for (int ks = 0; ks < 4; ks++)
                xb[ks] = *(const bf16x8*)(xb_base + n*2048 + ks*512);
            f32x4 y0 = {0.f,0.f,0.f,0.f}, y1 = {0.f,0.f,0.f,0.f};
            #pragma unroll
            for (int ks = 0; ks < 4; ks++) {
                acc[n][0] = mf(Wt[0][ks], xb[ks], acc[n][0]);   // root -> own acc
                acc[n][1] = mf(Wt[1][ks], xb[ks], acc[n][1]);
                y0 = mf(Wr[0][ks], xb[ks], y0);                 // rel -> transient
                y1 = mf(Wr[1][ks], xb[ks], y1);
            }
            #pragma unroll
            for (int e = 0; e < 4; e++)                          // scatter once per node
                if (e < ODEG[n]) {
                    acc[ODST[n][e]][0] += y0;
                    acc[ODST[n][e]][1] += y1;
                }
        }
        __syncthreads();   // all X reads done
        #pragma unroll
        for (int n = 0; n < 13; n++) {
            store_pk4(&Xs[n*2048 +  hcs0     *128 + wofs], acc[n][0]);
            store_pk4(&Xs[n*2048 + (hcs0 + 2)*128 + wofs], acc[n][1]);
        }
        __syncthreads();   // new X visible
    }

    // ---------------- decoder: out[g][j] = x[j+1]·W_dec + b_dec ----------------
    {
        const unsigned short* xdec = Xs + q*512 + c*8;
        float wd[32];
        #pragma unroll
        for (int i4 = 0; i4 < 8; i4++) {
            const float4 wv = *(const float4*)&W_dec[q*32 + i4*4];
            wd[i4*4+0] = wv.x; wd[i4*4+1] = wv.y; wd[i4*4+2] = wv.z; wd[i4*4+3] = wv.w;
        }
        const float bd = b_dec[0];
        for (int j = wave; j < 12; j += 4) {    // 3 joints per wave
            float s = 0.0f;
            #pragma unroll
            for (int hq = 0; hq < 4; hq++) {    // lane covers h = q*32 + hq*8 + hi
                const bf16x8 xv = *(const bf16x8*)(xdec + (j+1)*2048 + hq*128);
                #pragma unroll
                for (int hi2 = 0; hi2 < 8; hi2++)
                    s += (float)xv[hi2] * wd[hq*8 + hi2];
            }
            s += __shfl_xor(s, 16);
            s += __shfl_xor(s, 32);
            if (q == 0 && (g0 + c) < B)
                out[(g0 + c)*12 + j] = s + bd;
        }
    }
}

extern "C" void kernel_launch(void* const* d_in, const int* in_sizes, int n_in,
                              void* d_out, int out_size, void* d_ws, size_t ws_size,
                              hipStream_t stream) {
    const float* obs   = (const float*)d_in[0];
    const float* We_b  = (const float*)d_in[1];
    const float* be_b  = (const float*)d_in[2];
    const float* We_j  = (const float*)d_in[3];
    const float* be_j  = (const float*)d_in[4];
    const float* W_rel = (const float*)d_in[5];
    const float* W_root= (const float*)d_in[6];
    const float* b_rel = (const float*)d_in[7];
    const float* W_dec = (const float*)d_in[8];
    const float* b_dec = (const float*)d_in[9];
    float* out = (float*)d_out;
    __bf16* wsb = (__bf16*)d_ws;

    const int B = in_sizes[0] / OBSROW;
    convert_weights<<<(WS_TOT + 255) / 256, 256, 0, stream>>>(W_rel, W_root, We_b, We_j, wsb);
    const int blocks = (B + GPB - 1) / GPB;
    gnn_fused<<<blocks, NT, 0, stream>>>(obs, be_b, be_j, b_rel, W_dec, b_dec,
                                         wsb, out, B);
}

// Round 5
// 194.561 us; speedup vs baseline: 1.1524x; 1.1151x over previous
//
#include <hip/hip_runtime.h>

#define H      128
#define OBSROW 141
#define GPB    16     // graphs per block (MFMA M dimension)
#define NT     256    // 4 waves; each wave owns 32 output channels (2 x 16-subtiles)

typedef __bf16 bf16x8 __attribute__((ext_vector_type(8)));
typedef float  f32x4  __attribute__((ext_vector_type(4)));

__device__ __forceinline__ float eluf(float v) {
    return v > 0.0f ? v : (__expf(v) - 1.0f);
}
__device__ __forceinline__ f32x4 mf(bf16x8 a, bf16x8 b, f32x4 c) {
    return __builtin_amdgcn_mfma_f32_16x16x32_bf16(a, b, c, 0, 0, 0);
}
// elu 4 floats -> 4 bf16, one aligned b64 store
__device__ __forceinline__ void store_pk4(unsigned short* dst, f32x4 a) {
    union { unsigned short u[4]; unsigned long long v; } pk;
    #pragma unroll
    for (int r = 0; r < 4; r++) {
        __bf16 b = (__bf16)eluf(a[r]);
        pk.u[r] = *(unsigned short*)&b;
    }
    *(unsigned long long*)dst = pk.v;
}

// ws (bf16 elems): [0)Wrel 3*16384 | [49152)Wroot 3*16384 | [98304)We_b pad[128][64] | [106496)We_j pad[128][32]
#define WS_ROOT 49152
#define WS_EB   98304
#define WS_EJ   106496
#define WS_TOT  110592

__global__ void convert_weights(const float* __restrict__ Wr, const float* __restrict__ Wo,
                                const float* __restrict__ Web, const float* __restrict__ Wej,
                                __bf16* __restrict__ ws) {
    const int i = blockIdx.x * 256 + threadIdx.x;
    if (i < WS_ROOT) {
        ws[i] = (__bf16)Wr[i];
    } else if (i < WS_EB) {
        ws[i] = (__bf16)Wo[i - WS_ROOT];
    } else if (i < WS_EJ) {
        const int j = i - WS_EB, o = j >> 6, f = j & 63;
        ws[i] = (__bf16)(f < 33 ? Web[o*33 + f] : 0.0f);
    } else if (i < WS_TOT) {
        const int j = i - WS_EJ, o = j >> 5, f = j & 31;
        ws[i] = (__bf16)(f < 9 ? Wej[o*9 + f] : 0.0f);
    }
}

// X layout: [node 13][hc 16][graph 16][hi 8] bf16; k (= channel) = hc*8+hi
// Gathered features OVERLAY the top of Xs: ushort [19456, 26624) = node 9..12 region.
// Encoder outputs for nodes 9..12 are computed into registers, stored after a barrier.
#define G0U 19456   // joints jj at G0U+jj*512, base at G0U+6144

__launch_bounds__(NT, 3)   // 3 waves/EU -> 168-reg cap; peak demand ~145 (root/rel x
                           // K-half passes keep only 4 weight frags live) -> no spill.
                           // 3 blocks/CU (LDS 53248*3 = 159744 <= 163840)
__global__ void gnn_fused(const float* __restrict__ obs,
                          const float* __restrict__ be_b, const float* __restrict__ be_j,
                          const float* __restrict__ b_rel,
                          const float* __restrict__ W_dec, const float* __restrict__ b_dec,
                          const __bf16* __restrict__ wsb,
                          float* __restrict__ out, int B)
{
    __shared__ __align__(16) unsigned short Xs[13*2048];   // 53248 B total

    const int tid  = threadIdx.x;
    const int wave = tid >> 6;     // 0..3 -> channels [wave*32, wave*32+32)
    const int lane = tid & 63;
    const int q    = lane >> 4;    // k-quarter (inputs) / channel-quad (output)
    const int c    = lane & 15;    // graph (B-side) == weight output-row offset (A-side)
    const int g0   = blockIdx.x * GPB;

    static constexpr int ODEG[13]    = {4,2,2,1,2,2,1,2,2,1,2,2,1};
    static constexpr int ODST[13][4] = {
        {1,4,7,10},{0,2,0,0},{1,3,0,0},{2,0,0,0},{0,5,0,0},{4,6,0,0},{5,0,0,0},
        {0,8,0,0},{7,9,0,0},{8,0,0,0},{0,11,0,0},{10,12,0,0},{11,0,0,0}};

    // swapped-operand output: lane (q,c) holds graph c, channels o = wave*32+s*16+q*4+r
    const int hcs0 = wave*4 + (q>>1);          // hc for s=0 (s adds 2)
    const int wofs = c*8 + (q&1)*4;            // graph*8 + hi base (ushort units)

    // ---------------- stage 0: coalesced obs copy global -> LDS raw (bytes [0,9024)) ----
    {
        float* raw = (float*)Xs;
        for (int i = tid; i < GPB*OBSROW; i += NT) {
            const int g = i / OBSROW;
            raw[i] = ((g0 + g) < B) ? obs[(g0+g)*OBSROW + (i - g*OBSROW)] : 0.0f;
        }
    }
    __syncthreads();

    // ---------------- stage 1: gather + cvt raw -> gathered (top of Xs) ----------------
    {
        const float* raw = (const float*)Xs;
        for (int s = tid; s < 6144; s += NT) {
            const int jj = s >> 9, rem = s & 511;
            const int fc = rem >> 7, g = (rem >> 3) & 15, hi = rem & 7;
            const int f = fc*8 + hi;
            float v = 0.0f;
            if (f < 9)
                v = raw[g*OBSROW + (f/3)*47 + 9 + (f%3)*12 + jj];
            *(__bf16*)&Xs[G0U + s] = (__bf16)v;
        }
        for (int s = tid; s < 1024; s += NT) {
            const int fc = s >> 7, rem = s & 127, g = rem >> 3, hi = rem & 7;
            const int f = fc*8 + hi;
            float v = 0.0f;
            if (f < 33) {
                const int tt = f / 11, i2 = f % 11;
                v = raw[g*OBSROW + tt*47 + (i2 < 9 ? i2 : 36 + i2)];
            }
            *(__bf16*)&Xs[G0U + 6144 + s] = (__bf16)v;
        }
    }
    __syncthreads();

    // ---------------- encoders (A = weights, B = features) ----------------
    // Nodes 0..8 outputs (ushort [0,18432)) don't overlap gathered ([19456,26624)) -> direct.
    // Nodes 9..12 outputs overlap gathered -> accumulate in regs, store after barrier.
    {
        const int orow = wave*32 + c;
        // node 0 (base), K=64 padded
        const bf16x8 a0 = *(const bf16x8*)&Xs[G0U + 6144 + q*128 + c*8];
        const bf16x8 a1 = *(const bf16x8*)&Xs[G0U + 6144 + 512 + q*128 + c*8];
        #pragma unroll
        for (int s = 0; s < 2; s++) {
            const bf16x8 u0 = *(const bf16x8*)(wsb + WS_EB + (orow + s*16)*64 + q*8);
            const bf16x8 u1 = *(const bf16x8*)(wsb + WS_EB + (orow + s*16)*64 + 32 + q*8);
            const float4 b4 = *(const float4*)&be_b[wave*32 + s*16 + q*4];
            f32x4 acc = {b4.x, b4.y, b4.z, b4.w};
            acc = mf(u0, a0, acc);
            acc = mf(u1, a1, acc);
            store_pk4(&Xs[(hcs0 + s*2)*128 + wofs], acc);
        }
        // joints 0..11, K=32; hoist the two weight frags and biases
        bf16x8 uj[2];
        f32x4 bias[2];
        #pragma unroll
        for (int s = 0; s < 2; s++) {
            uj[s] = *(const bf16x8*)(wsb + WS_EJ + (orow + s*16)*32 + q*8);
            const float4 b4 = *(const float4*)&be_j[wave*32 + s*16 + q*4];
            bias[s] = (f32x4){b4.x, b4.y, b4.z, b4.w};
        }
        f32x4 dacc[2][4];   // deferred: nodes 9..12
        #pragma unroll
        for (int jj = 0; jj < 12; jj++) {
            const bf16x8 a = *(const bf16x8*)&Xs[G0U + jj*512 + q*128 + c*8];
            #pragma unroll
            for (int s = 0; s < 2; s++) {
                f32x4 acc = bias[s];
                acc = mf(uj[s], a, acc);
                if (jj < 8)
                    store_pk4(&Xs[(1+jj)*2048 + (hcs0 + s*2)*128 + wofs], acc);
                else
                    dacc[s][jj-8] = acc;
            }
        }
        __syncthreads();   // all gathered-feature reads complete
        #pragma unroll
        for (int t = 0; t < 4; t++) {
            store_pk4(&Xs[(9+t)*2048 +  hcs0     *128 + wofs], dacc[0][t]);
            store_pk4(&Xs[(9+t)*2048 + (hcs0+2)  *128 + wofs], dacc[1][t]);
        }
    }
    __syncthreads();

    // ---------------- 3 GraphConv layers ----------------
    // B-frag (X) for (n,ks): Xs + n*2048 + ks*512 + q*128 + c*8 (wave-contiguous 1KB)
    // Layer = root pass + rel pass, each split over K-halves: only 4 weight frags +
    // 2 X frags + y live at any time -> peak regs ~145 < 168 cap.
    const unsigned short* xb_base = Xs + q*128 + c*8;
    #pragma unroll 1
    for (int l = 0; l < 3; l++) {
        const __bf16* wrp = wsb + l*16384;            // W_rel[l][o][h]
        const __bf16* wop = wsb + WS_ROOT + l*16384;  // W_root[l][o][h]
        const int row0 = (wave*32 +  0 + c)*128 + q*8;
        const int row1 = (wave*32 + 16 + c)*128 + q*8;

        f32x4 acc[13][2];
        #pragma unroll
        for (int s = 0; s < 2; s++) {
            const float4 b4 = *(const float4*)&b_rel[l*H + wave*32 + s*16 + q*4];
            const f32x4 bias = {b4.x, b4.y, b4.z, b4.w};
            #pragma unroll
            for (int n = 0; n < 13; n++) acc[n][s] = bias;
        }

        // ---- ROOT: acc[n] += W_root x[n], K-halves ----
        #pragma unroll 1
        for (int h = 0; h < 2; h++) {
            const bf16x8 w00 = *(const bf16x8*)(wop + row0 + (2*h+0)*32);
            const bf16x8 w01 = *(const bf16x8*)(wop + row0 + (2*h+1)*32);
            const bf16x8 w10 = *(const bf16x8*)(wop + row1 + (2*h+0)*32);
            const bf16x8 w11 = *(const bf16x8*)(wop + row1 + (2*h+1)*32);
            const unsigned short* xh = xb_base + 2*h*512;
            #pragma unroll
            for (int n = 0; n < 13; n++) {
                const bf16x8 xa0 = *(const bf16x8*)(xh + n*2048);
                const bf16x8 xa1 = *(const bf16x8*)(xh + n*2048 + 512);
                acc[n][0] = mf(w00, xa0, acc[n][0]);
                acc[n][0] = mf(w01, xa1, acc[n][0]);
                acc[n][1] = mf(w10, xa0, acc[n][1]);
                acc[n][1] = mf(w11, xa1, acc[n][1]);
            }
        }

        // ---- REL: acc[dst] += W_rel x[n] for each out-edge, K-halves ----
        #pragma unroll 1
        for (int h = 0; h < 2; h++) {
            const bf16x8 r00 = *(const bf16x8*)(wrp + row0 + (2*h+0)*32);
            const bf16x8 r01 = *(const bf16x8*)(wrp + row0 + (2*h+1)*32);
            const bf16x8 r10 = *(const bf16x8*)(wrp + row1 + (2*h+0)*32);
            const bf16x8 r11 = *(const bf16x8*)(wrp + row1 + (2*h+1)*32);
            const unsigned short* xh = xb_base + 2*h*512;
            #pragma unroll
            for (int n = 0; n < 13; n++) {
                const bf16x8 xa0 = *(const bf16x8*)(xh + n*2048);
                const bf16x8 xa1 = *(const bf16x8*)(xh + n*2048 + 512);
                if (ODEG[n] == 1) {
                    // single out-neighbor: MFMA straight into its accumulator
                    const int d = ODST[n][0];
                    acc[d][0] = mf(r00, xa0, acc[d][0]);
                    acc[d][0] = mf(r01, xa1, acc[d][0]);
                    acc[d][1] = mf(r10, xa0, acc[d][1]);
                    acc[d][1] = mf(r11, xa1, acc[d][1]);
                } else {
                    f32x4 y0 = {0.f,0.f,0.f,0.f}, y1 = {0.f,0.f,0.f,0.f};
                    y0 = mf(r00, xa0, y0);
                    y0 = mf(r01, xa1, y0);
                    y1 = mf(r10, xa0, y1);
                    y1 = mf(r11, xa1, y1);
                    #pragma unroll
                    for (int e = 0; e < 4; e++)
                        if (e < ODEG[n]) {
                            acc[ODST[n][e]][0] += y0;
                            acc[ODST[n][e]][1] += y1;
                        }
                }
            }
        }

        __syncthreads();   // all X reads done
        #pragma unroll
        for (int n = 0; n < 13; n++) {
            store_pk4(&Xs[n*2048 +  hcs0     *128 + wofs], acc[n][0]);
            store_pk4(&Xs[n*2048 + (hcs0 + 2)*128 + wofs], acc[n][1]);
        }
        __syncthreads();   // new X visible
    }

    // ---------------- decoder: out[g][j] = x[j+1]·W_dec + b_dec ----------------
    {
        const unsigned short* xdec = Xs + q*512 + c*8;
        float wd[32];
        #pragma unroll
        for (int i4 = 0; i4 < 8; i4++) {
            const float4 wv = *(const float4*)&W_dec[q*32 + i4*4];
            wd[i4*4+0] = wv.x; wd[i4*4+1] = wv.y; wd[i4*4+2] = wv.z; wd[i4*4+3] = wv.w;
        }
        const float bd = b_dec[0];
        for (int j = wave; j < 12; j += 4) {    // 3 joints per wave
            float s = 0.0f;
            #pragma unroll
            for (int hq = 0; hq < 4; hq++) {    // lane covers h = q*32 + hq*8 + hi
                const bf16x8 xv = *(const bf16x8*)(xdec + (j+1)*2048 + hq*128);
                #pragma unroll
                for (int hi2 = 0; hi2 < 8; hi2++)
                    s += (float)xv[hi2] * wd[hq*8 + hi2];
            }
            s += __shfl_xor(s, 16);
            s += __shfl_xor(s, 32);
            if (q == 0 && (g0 + c) < B)
                out[(g0 + c)*12 + j] = s + bd;
        }
    }
}

extern "C" void kernel_launch(void* const* d_in, const int* in_sizes, int n_in,
                              void* d_out, int out_size, void* d_ws, size_t ws_size,
                              hipStream_t stream) {
    const float* obs   = (const float*)d_in[0];
    const float* We_b  = (const float*)d_in[1];
    const float* be_b  = (const float*)d_in[2];
    const float* We_j  = (const float*)d_in[3];
    const float* be_j  = (const float*)d_in[4];
    const float* W_rel = (const float*)d_in[5];
    const float* W_root= (const float*)d_in[6];
    const float* b_rel = (const float*)d_in[7];
    const float* W_dec = (const float*)d_in[8];
    const float* b_dec = (const float*)d_in[9];
    float* out = (float*)d_out;
    __bf16* wsb = (__bf16*)d_ws;

    const int B = in_sizes[0] / OBSROW;
    convert_weights<<<(WS_TOT + 255) / 256, 256, 0, stream>>>(W_rel, W_root, We_b, We_j, wsb);
    const int blocks = (B + GPB - 1) / GPB;
    gnn_fused<<<blocks, NT, 0, stream>>>(obs, be_b, be_j, b_rel, W_dec, b_dec,
                                         wsb, out, B);
}